// Round 1
// baseline (72.586 us; speedup 1.0000x reference)
//
#include <hip/hip_runtime.h>

#define RADIUS 5
#define WIN    11
#define WIN2   121
#define KCLS   6
#define HH     128
#define WW     128
#define BB     4
#define NPIX   (HH*WW)
#define RPB    2                    // rows per block
#define NBLK   (BB*HH/RPB)          // 256 blocks
#define TPB    256
#define LABW   138                  // columns -5..132
#define LABH   (RPB + 2*RADIUS)     // 12 rows
#define LABSZ  (KCLS*LABH*LABW)     // 9936 floats
#define OCH    16                   // o-chunk
#define WPAD   17                   // padded stride to avoid bank conflicts
#define TOTW   ((size_t)BB*NPIX*WIN2)

__global__ __launch_bounds__(TPB) void ncut_main(
    const float* __restrict__ labels,
    const float* __restrict__ weights,
    float* __restrict__ part) {
  __shared__ float shl[LABSZ];        // 39744 B label tile (zero-padded)
  __shared__ float shw[TPB * WPAD];   // 17408 B weights o-chunk

  const int tid = threadIdx.x;
  const int blk = blockIdx.x;
  const int b   = blk >> 6;                 // 64 blocks per batch image
  const int y0  = (blk & 63) * RPB;

  // ---- stage zero-padded label tile: K x 12 x 138 ----
  const float* labB = labels + (size_t)b * KCLS * NPIX;
  for (int idx = tid; idx < LABSZ; idx += TPB) {
    int k  = idx / (LABH * LABW);
    int rm = idx - k * (LABH * LABW);
    int tr = rm / LABW;
    int tc = rm - tr * LABW;
    int gy = y0 - RADIUS + tr;
    int gx = tc - RADIUS;
    float v = 0.0f;
    if ((unsigned)gy < (unsigned)HH && (unsigned)gx < (unsigned)WW)
      v = labB[((size_t)k * HH + gy) * WW + gx];
    shl[idx] = v;
  }

  // ---- per-thread pixel ----
  const int r = tid >> 7;          // row within block: 0/1
  const int x = tid & (WW - 1);
  const size_t P0 = (size_t)b * NPIX + (size_t)y0 * WW;   // first pixel of block
  const float* wB = weights + P0 * WIN2;

  float wp[KCLS] = {0.f, 0.f, 0.f, 0.f, 0.f, 0.f};
  float wsum = 0.f;
  const int lbase = r * LABW + x;

#pragma unroll
  for (int c = 0; c < 8; ++c) {
    const int o0 = c * OCH;
    __syncthreads();   // protect shw from previous chunk's readers
    // stage TPB*16 weight values, coalesced in runs of 16 floats
#pragma unroll
    for (int i = 0; i < OCH; ++i) {
      int t  = tid + i * TPB;
      int p  = t >> 4;
      int oo = t & 15;
      size_t gi = (size_t)p * WIN2 + (size_t)(o0 + oo);
      if (P0 * WIN2 + gi >= TOTW) gi = 0;   // clamp (slot never used in compute)
      shw[p * WPAD + oo] = wB[gi];
    }
    __syncthreads();
    const float* wrow = &shw[tid * WPAD];
#pragma unroll
    for (int j = 0; j < OCH; ++j) {
      const int o = o0 + j;
      if (o >= WIN2) break;                 // compile-time under full unroll
      const int oy = o / WIN;
      const int ox = o - oy * WIN;
      const float w = wrow[j];
      wsum += w;
      const int li = lbase + oy * LABW + ox;
#pragma unroll
      for (int k = 0; k < KCLS; ++k)
        wp[k] += w * shl[li + k * (LABH * LABW)];
    }
  }

  // ---- per-thread num/den, then block reduce ----
  const int ce = lbase + RADIUS * LABW + RADIUS;   // center pixel in tile
  float nv[KCLS], dv[KCLS];
#pragma unroll
  for (int k = 0; k < KCLS; ++k) {
    const float p = shl[ce + k * (LABH * LABW)];
    nv[k] = p * wp[k];
    dv[k] = p * wsum;
  }

  __syncthreads();                  // done reading shw; reuse as reduce buffer
  float* shred = shw;               // [4 waves][12]

#pragma unroll
  for (int k = 0; k < KCLS; ++k) {
    float n = nv[k], d = dv[k];
#pragma unroll
    for (int off = 32; off; off >>= 1) {
      n += __shfl_down(n, off);
      d += __shfl_down(d, off);
    }
    if ((tid & 63) == 0) {
      shred[(tid >> 6) * 12 + k]     = n;
      shred[(tid >> 6) * 12 + 6 + k] = d;
    }
  }
  __syncthreads();
  if (tid < 12) {
    float s = shred[tid] + shred[12 + tid] + shred[24 + tid] + shred[36 + tid];
    part[blk * 12 + tid] = s;
  }
}

// ---- final: L = num/den per (b,k); out = K - 0.25 * sum |L| ----
__global__ __launch_bounds__(64) void ncut_final(
    const float* __restrict__ part, float* __restrict__ out) {
  const int t = threadIdx.x;
  float val = 0.f;
  if (t < BB * KCLS) {
    const int b = t / KCLS;
    const int k = t - b * KCLS;
    float num = 0.f, den = 0.f;
    for (int j = 0; j < 64; ++j) {
      const float* p = part + (size_t)(b * 64 + j) * 12;
      num += p[k];
      den += p[6 + k];
    }
    val = fabsf(num / den) * (1.0f / BB);
  }
#pragma unroll
  for (int off = 32; off; off >>= 1) val += __shfl_down(val, off);
  if (t == 0) out[0] = (float)KCLS - val;
}

extern "C" void kernel_launch(void* const* d_in, const int* in_sizes, int n_in,
                              void* d_out, int out_size, void* d_ws, size_t ws_size,
                              hipStream_t stream) {
  const float* labels  = (const float*)d_in[0];
  const float* weights = (const float*)d_in[1];
  float* out  = (float*)d_out;
  float* part = (float*)d_ws;      // 256 blocks * 12 floats = 12288 B

  ncut_main<<<NBLK, TPB, 0, stream>>>(labels, weights, part);
  ncut_final<<<1, 64, 0, stream>>>(part, out);
}

// Round 2
// 27.511 us; speedup vs baseline: 2.6385x; 2.6385x over previous
//
#include <hip/hip_runtime.h>

#define RADIUS 5
#define WIN    11
#define WIN2   121
#define KCLS   6
#define HH     128
#define WW     128
#define BB     4
#define NPIX   (HH*WW)
#define TPB    512                  // 4 threads per pixel, 128 px (one row)
#define NBLK   (BB*HH)              // 512 blocks, one image row each
#define LABW   138                  // cols -5..132
#define LABH   WIN                  // rows y0-5..y0+5
#define LABPL  (LABH*LABW)          // 1518 floats per class plane
#define LABSZ  (KCLS*LABPL)         // 9108 floats = 36.4 KB

__global__ __launch_bounds__(TPB) void ncut_main(
    const float* __restrict__ labels,
    const float* __restrict__ weights,
    float* __restrict__ part) {
  __shared__ float shl[LABSZ];      // zero-padded label tile, K x 11 x 138
  __shared__ int   shtab[128];      // o -> oy*LABW+ox
  __shared__ float shred[8 * 12];   // per-wave partials

  const int tid = threadIdx.x;
  const int blk = blockIdx.x;
  const int b   = blk >> 7;
  const int y0  = blk & (HH - 1);

  if (tid < WIN2) shtab[tid] = (tid / WIN) * LABW + (tid % WIN);

  // ---- stage zero-padded label tile ----
  const float* labB = labels + (size_t)b * KCLS * NPIX;
  for (int idx = tid; idx < LABSZ; idx += TPB) {
    int k  = idx / LABPL;
    int rm = idx - k * LABPL;
    int tr = rm / LABW;
    int tc = rm - tr * LABW;
    int gy = y0 - RADIUS + tr;
    int gx = tc - RADIUS;
    float v = 0.0f;
    if ((unsigned)gy < (unsigned)HH && (unsigned)gx < (unsigned)WW)
      v = labB[((size_t)k * HH + gy) * WW + gx];
    shl[idx] = v;
  }
  __syncthreads();

  // ---- per-thread: pixel px, window-quarter q ----
  const int px = tid >> 2;          // 0..127
  const int q  = tid & 3;           // 0..3
  const int o0 = q * 30;            // 30,30,30,(30+tail)
  const float* wrow = weights +
      ((size_t)b * NPIX + (size_t)y0 * WW + px) * WIN2 + o0;

  float wp[KCLS] = {0.f, 0.f, 0.f, 0.f, 0.f, 0.f};
  float wsum = 0.f;

#pragma unroll 6
  for (int j = 0; j < 30; ++j) {
    const float w = wrow[j];
    wsum += w;
    const int li = px + shtab[o0 + j];
#pragma unroll
    for (int k = 0; k < KCLS; ++k)
      wp[k] += w * shl[li + k * LABPL];
  }
  if (q == 3) {                     // tail: o = 120
    const float w = wrow[30];
    wsum += w;
    const int li = px + shtab[120];
#pragma unroll
    for (int k = 0; k < KCLS; ++k)
      wp[k] += w * shl[li + k * LABPL];
  }

  // ---- reduce across the 4 q-lanes (adjacent lanes) ----
#pragma unroll
  for (int off = 1; off <= 2; off <<= 1) {
    wsum += __shfl_xor(wsum, off);
#pragma unroll
    for (int k = 0; k < KCLS; ++k) wp[k] += __shfl_xor(wp[k], off);
  }

  // ---- num/den per pixel (all 4 q-lanes hold identical values) ----
  const int ce = px + RADIUS * LABW + RADIUS;   // center offset
  float nv[KCLS], dv[KCLS];
#pragma unroll
  for (int k = 0; k < KCLS; ++k) {
    const float p = shl[ce + k * LABPL];
    nv[k] = p * wp[k];
    dv[k] = p * wsum;
  }

  // ---- reduce across the 16 pixels of this wave (lane bits 2..5) ----
#pragma unroll
  for (int off = 4; off <= 32; off <<= 1) {
#pragma unroll
    for (int k = 0; k < KCLS; ++k) {
      nv[k] += __shfl_xor(nv[k], off);
      dv[k] += __shfl_xor(dv[k], off);
    }
  }
  const int wave = tid >> 6;
  if ((tid & 63) == 0) {
#pragma unroll
    for (int k = 0; k < KCLS; ++k) {
      shred[wave * 12 + k]     = nv[k];
      shred[wave * 12 + 6 + k] = dv[k];
    }
  }
  __syncthreads();
  if (tid < 12) {
    float s = 0.f;
#pragma unroll
    for (int w = 0; w < 8; ++w) s += shred[w * 12 + tid];
    part[blk * 12 + tid] = s;
  }
}

// ---- final: L = num/den per (b,k); out = K - (1/B) * sum |L| ----
__global__ __launch_bounds__(64) void ncut_final(
    const float* __restrict__ part, float* __restrict__ out) {
  const int t = threadIdx.x;
  float val = 0.f;
  if (t < BB * KCLS) {
    const int b = t / KCLS;
    const int k = t - b * KCLS;
    float num = 0.f, den = 0.f;
    for (int j = 0; j < HH; ++j) {
      const float* p = part + (size_t)(b * HH + j) * 12;
      num += p[k];
      den += p[6 + k];
    }
    val = fabsf(num / den) * (1.0f / BB);
  }
#pragma unroll
  for (int off = 32; off; off >>= 1) val += __shfl_down(val, off);
  if (t == 0) out[0] = (float)KCLS - val;
}

extern "C" void kernel_launch(void* const* d_in, const int* in_sizes, int n_in,
                              void* d_out, int out_size, void* d_ws, size_t ws_size,
                              hipStream_t stream) {
  const float* labels  = (const float*)d_in[0];
  const float* weights = (const float*)d_in[1];
  float* out  = (float*)d_out;
  float* part = (float*)d_ws;      // 512 blocks * 12 floats = 24576 B

  ncut_main<<<NBLK, TPB, 0, stream>>>(labels, weights, part);
  ncut_final<<<1, 64, 0, stream>>>(part, out);
}